// Round 17
// baseline (173.722 us; speedup 1.0000x reference)
//
#include <hip/hip_runtime.h>
#include <stdint.h>
#include <math.h>

// ---------- types ----------
typedef __attribute__((ext_vector_type(8))) __bf16 bf16x8;
typedef __attribute__((ext_vector_type(4))) float f32x4;
typedef __attribute__((ext_vector_type(16))) float f32x16;

__device__ __forceinline__ uint32_t f32_to_bf16_rne(float f) {
  union { float f; uint32_t u; } v; v.f = f;
  return (v.u + 0x7FFFu + ((v.u >> 16) & 1u)) >> 16;
}

__device__ __forceinline__ uint32_t cvt_pk_bf16(float lo, float hi) {
  uint32_t r;
  asm("v_cvt_pk_bf16_f32 %0, %1, %2" : "=v"(r) : "v"(lo), "v"(hi));
  return r;
}

__device__ __forceinline__ void gld16(void* lds, const void* g) {
  __builtin_amdgcn_global_load_lds(
      (__attribute__((address_space(1))) void*)(g),
      (__attribute__((address_space(3))) void*)(lds), 16, 0, 0);
}

__device__ __forceinline__ f32x4 mfma16(bf16x8 a, bf16x8 b, f32x4 c) {
  return __builtin_amdgcn_mfma_f32_16x16x32_bf16(a, b, c, 0, 0, 0);
}
__device__ __forceinline__ f32x16 mfma32(bf16x8 a, bf16x8 b, f32x16 c) {
  return __builtin_amdgcn_mfma_f32_32x32x16_bf16(a, b, c, 0, 0, 0);
}

#define LOG2E 1.44269504088896340736f

// ---------- kernel 1: fused converts (x fp32->bf16 ; W transpose->bf16) ------
__global__ __launch_bounds__(256) void k_convert(const float* __restrict__ x,
                                                 const float* __restrict__ wq,
                                                 const float* __restrict__ wkv,
                                                 uint16_t* __restrict__ xb,
                                                 uint16_t* __restrict__ wt) {
  __shared__ float tile[64][65];
  int blk = blockIdx.x;
  int t = threadIdx.x;
  if (blk < 2048) {  // x: one thread per 8 elements
    int i = blk * 256 + t;
    const float4* xv = (const float4*)x;
    float4 a = xv[2 * i], b2 = xv[2 * i + 1];
    uint32_t w0 = f32_to_bf16_rne(a.x) | (f32_to_bf16_rne(a.y) << 16);
    uint32_t w1 = f32_to_bf16_rne(a.z) | (f32_to_bf16_rne(a.w) << 16);
    uint32_t w2 = f32_to_bf16_rne(b2.x) | (f32_to_bf16_rne(b2.y) << 16);
    uint32_t w3 = f32_to_bf16_rne(b2.z) | (f32_to_bf16_rne(b2.w) << 16);
    ((uint4*)xb)[i] = make_uint4(w0, w1, w2, w3);
  } else {  // W: tiled transpose into Wt[c][k]
    int blk2 = blk - 2048;
    int c0 = (blk2 % 24) * 64, k0 = (blk2 / 24) * 64;
    int col = t & 63, rq = t >> 6;
#pragma unroll
    for (int rr = 0; rr < 16; rr++) {
      int r = rr * 4 + rq;
      int c = c0 + col;
      float v = (c < 1024) ? wq[(uint64_t)(k0 + r) * 1024 + c]
                           : wkv[(uint64_t)(k0 + r) * 512 + (c - 1024)];
      tile[r][col] = v;
    }
    __syncthreads();
#pragma unroll
    for (int rr = 0; rr < 16; rr++) {
      int a = rr * 4 + rq;  // output row (c-local)
      wt[(uint64_t)(c0 + a) * 1024 + k0 + col] = (uint16_t)f32_to_bf16_rne(tile[col][a]);
    }
  }
}

// ---------- kernel 2: projection GEMM, BK=64 ring-3, XCD row-panel pinned ----
// 128x64 tile, 768 blocks. Remap: xcd = id%8 owns m-panels [xcd*512,+512) ->
// each XCD's working set = 4 A-panels (1 MB) + B (3 MB) = its 4 MB L2.
// Per K-step: stage(t+2) -> readFrags(t) [proven LAST iter] -> MFMA(t) ->
// vmcnt(6)+lgkmcnt(0)+barrier (compute before the convoy wait).
// Epilogue: q row-major, K/V in SUBTILE-LINEAR fragment order:
//  K frag g = gsu*4 + m    : K[kv=32*gsu + lrr][d=16m + 8hh + el]
//  V frag g = gsu*4+dd*2+jj: V[kv=32*gsu + 16jj + 8hh + el][d=32dd + lrr]
__global__ __launch_bounds__(256, 2) void k_proj_gemm(
    const uint16_t* __restrict__ xb, const uint16_t* __restrict__ wt,
    const float* __restrict__ kscale, uint16_t* __restrict__ q_ws,
    uint16_t* __restrict__ kf_ws, uint16_t* __restrict__ vf_ws) {
  __shared__ __align__(16) uint16_t ring[3][12288];  // slot: A 8192 u16 + B 4096 u16
  int t = threadIdx.x;
  int w = t >> 6, l = t & 63;
  int lq = l & 15, lg = l >> 4;
  // XCD-pinned remap: id%8 = XCD; XCD x computes m-rows [x*512, x*512+512)
  int id = blockIdx.x;
  int xcd = id & 7, idx = id >> 3;        // idx 0..95
  int rrp = idx & 3, cc = idx >> 2;       // 4 row-panels x 24 col-tiles
  int m0 = (xcd * 4 + rrp) * 128, n0 = cc * 64;
  int wr = w >> 1, wc = w & 1;  // 2x2 waves: 64 rows x 32 cols each
  f32x4 acc[4][2] = {};

  auto stage = [&](int slot, int k0) {
#pragma unroll
    for (int j = 0; j < 4; j++) {  // A: 128 rows x 64 cols = 1024 chunks of 16B
      int c = j * 256 + t;
      int r = c >> 3, s = c & 7;
      int sl = s ^ (r & 7);
      gld16((char*)&ring[slot][0] + c * 16,
            xb + (uint64_t)(m0 + r) * 1024 + k0 + sl * 8);
    }
#pragma unroll
    for (int j = 0; j < 2; j++) {  // B: 64 rows x 64 cols = 512 chunks
      int c = j * 256 + t;
      int r = c >> 3, s = c & 7;
      int sl = s ^ (r & 7);
      gld16((char*)&ring[slot][8192] + c * 16,
            wt + (uint64_t)(n0 + r) * 1024 + k0 + sl * 8);
    }
  };

  stage(0, 0);
  stage(1, 64);
  asm volatile("s_waitcnt vmcnt(6)" ::: "memory");  // slot 0 proven
  __builtin_amdgcn_s_barrier();

  for (int it = 0; it < 16; ++it) {
    // stage(t+2); dummies at the tail re-stage byte-identical data
    int tn = it + 2;
    int kn = (tn < 16) ? tn * 64 : (tn - 3) * 64;
    stage(tn % 3, kn);

    // read frags of slot it (proven by LAST iteration's vmcnt+barrier)
    const uint16_t* As = &ring[it % 3][0];
    const uint16_t* Bs = &ring[it % 3][8192];
    bf16x8 af[2][4], bfr[2][2];
#pragma unroll
    for (int kk = 0; kk < 2; kk++) {
#pragma unroll
      for (int m = 0; m < 4; m++) {
        int r = wr * 64 + m * 16 + lq;
        int sl = (kk * 4 + lg) ^ (r & 7);
        af[kk][m] = *(const bf16x8*)(As + r * 64 + sl * 8);
      }
#pragma unroll
      for (int n = 0; n < 2; n++) {
        int r = wc * 32 + n * 16 + lq;
        int sl = (kk * 4 + lg) ^ (r & 7);
        bfr[kk][n] = *(const bf16x8*)(Bs + r * 64 + sl * 8);
      }
    }
    __builtin_amdgcn_s_setprio(1);
#pragma unroll
    for (int kk = 0; kk < 2; kk++)
#pragma unroll
      for (int m = 0; m < 4; m++)
#pragma unroll
        for (int n = 0; n < 2; n++)
          acc[m][n] = mfma16(af[kk][m], bfr[kk][n], acc[m][n]);
    __builtin_amdgcn_s_setprio(0);

    // convoy AFTER compute: proves slot it+1 for next iter; lgkm drains the
    // ds_reads of slot it before anyone re-stages it (slot (it+3)%3 == it%3).
    asm volatile("s_waitcnt vmcnt(6) lgkmcnt(0)" ::: "memory");
    __builtin_amdgcn_s_barrier();
  }

#pragma unroll
  for (int m = 0; m < 4; m++)
#pragma unroll
    for (int n = 0; n < 2; n++)
#pragma unroll
      for (int jj = 0; jj < 4; jj++) {
        int row = m0 + wr * 64 + m * 16 + 4 * lg + jj;  // b*2048+n
        int col = n0 + wc * 32 + n * 16 + lq;           // 0..1535
        float val = acc[m][n][jj];
        int b = row >> 11, nn = row & 2047;
        if (col < 1024) {
          // fold qk-norm scale, 1/sqrt(64), and log2(e) (for exp2 softmax) into q
          val *= kscale[col] * 0.125f * LOG2E;
          q_ws[((uint64_t)((b * 16 + (col >> 6)) * 2048 + nn)) * 64 + (col & 63)] =
              (uint16_t)f32_to_bf16_rne(val);
        } else if (col < 1280) {
          int kvh = (col - 1024) >> 6;
          int d = col & 63;
          int gsu = nn >> 5, lrr = nn & 31;
          int mm = d >> 4, hh = (d >> 3) & 1, el = d & 7;
          kf_ws[(uint64_t)(b * 4 + kvh) * 131072 +
                (uint64_t)((((gsu * 4 + mm) * 64) + hh * 32 + lrr) * 8 + el)] =
              (uint16_t)f32_to_bf16_rne(val);
        } else {
          int kvh = (col - 1280) >> 6;
          int d = col & 63;
          int gsu = nn >> 5, jj2 = (nn >> 4) & 1, hh = (nn >> 3) & 1, el = nn & 7;
          int dd = d >> 5, lrr = d & 31;
          vf_ws[(uint64_t)(b * 4 + kvh) * 131072 +
                (uint64_t)((((gsu * 4 + dd * 2 + jj2) * 64) + hh * 32 + lrr) * 8 + el)] =
              (uint16_t)f32_to_bf16_rne(val);
        }
      }
}

// ---------- kernel 3: flash attention, 4-wave blocks, 2 blocks/CU ----------
// 512 blocks x 256 thr: 4 waves = 2 q-groups (64 rows) x 2 kv-halves; 128
// q-rows/block, 2 blocks/CU -> 4 waves/SIMD in two INDEPENDENT barrier
// domains (phases drift freely). Ring-4 x 16 KB = 64 KB. Per tile: stage
// su+3 (4 gld16/wave) -> compute su -> vmcnt(8)+lgkmcnt(0) (proves su+1;
// su+2/su+3 stay in flight) -> barrier. Slot (su+3)&3 consumed at su-1,
// one barrier ago -> overwrite-safe.
// No max-subtraction softmax (log2-domain scores bounded; partials additive).
__global__ __launch_bounds__(256, 4) void k_attn(const uint16_t* __restrict__ q_ws,
                                                 const uint16_t* __restrict__ kf_ws,
                                                 const uint16_t* __restrict__ vf_ws,
                                                 float* __restrict__ out) {
  extern __shared__ __align__(16) char smem[];  // 64 KB ring-4

  int t = threadIdx.x, w = t >> 6, l = t & 63;
  int lr = l & 31, hi = l >> 5;
  int qg = w & 1, half = w >> 1;
  // XCD-pinned remap: all blocks sharing (b,kvh) land on one XCD (blk%8 = XCD)
  int blk = blockIdx.x;
  int c = blk & 7, j = blk >> 3;  // j 0..63
  int b = c >> 2, kvh = c & 3;
  int h = kvh * 4 + (j >> 4), qb = j & 15;

  const uint16_t* Qb = q_ws + (uint64_t)(b * 16 + h) * 2048 * 64;
  const uint16_t* Kb = kf_ws + (uint64_t)(b * 4 + kvh) * 131072;
  const uint16_t* Vb = vf_ws + (uint64_t)(b * 4 + kvh) * 131072;
  int qrow0 = qb * 128 + qg * 64;  // this wave's 64 q-rows

  // Q B-frags for both 32-row subtiles
  bf16x8 qfA[4], qfB[4];
#pragma unroll
  for (int m = 0; m < 4; m++) {
    qfA[m] = *(const bf16x8*)(Qb + (uint64_t)(qrow0 + lr) * 64 + m * 16 + hi * 8);
    qfB[m] = *(const bf16x8*)(Qb + (uint64_t)(qrow0 + 32 + lr) * 64 + m * 16 + hi * 8);
  }

  f32x16 oaccA[2] = {}, oaccB[2] = {};
  float lA = 0.f, lB = 0.f;

  // staging: wave (qg,half) stages the (qg ? V : K) frags of ITS half: 4 gld16
  const uint16_t* SbW = (qg ? Vb : Kb) + (uint64_t)half * 65536 + l * 8;
  char* dstW = smem + half * 8192 + qg * 4096 + l * 16;

  auto stage = [&](int slot, int sul) {
    char* d = dstW + slot * 16384;
    const uint16_t* s = SbW + (uint64_t)sul * 2048;
#pragma unroll
    for (int f = 0; f < 4; f++) gld16(d + f * 1024, s + f * 512);
  };
  auto slotbase = [&](int slot) {
    return (const uint16_t*)(smem + slot * 16384 + half * 8192);
  };

  auto qk = [&](const bf16x8* kf, const bf16x8* qf) {
    f32x16 T = {};
    __builtin_amdgcn_s_setprio(1);
#pragma unroll
    for (int m = 0; m < 4; m++) T = mfma32(kf[m], qf[m], T);
    __builtin_amdgcn_s_setprio(0);
    return T;
  };

  // finish one 32-row subtile: softmax (exp2, no max shift), pack, PV
  auto finish = [&](f32x16& Tc, const bf16x8* vf, f32x16* oacc, float& lsum) {
    float p[16];
#pragma unroll
    for (int e = 0; e < 16; e++) p[e] = __builtin_amdgcn_exp2f(Tc[e]);
    float sm0 = ((p[0] + p[1]) + (p[2] + p[3])) + ((p[4] + p[5]) + (p[6] + p[7]));
    float sm1 = ((p[8] + p[9]) + (p[10] + p[11])) + ((p[12] + p[13]) + (p[14] + p[15]));
    lsum += sm0 + sm1;  // cross-half-lane shfl deferred to after the loop

    bf16x8 pa[2];
#pragma unroll
    for (int jj = 0; jj < 2; jj++) {
      const float* pp = p + 8 * jj;
      uint32_t X = cvt_pk_bf16(pp[0], pp[1]);
      uint32_t Z = cvt_pk_bf16(pp[2], pp[3]);
      uint32_t Y = cvt_pk_bf16(pp[4], pp[5]);
      uint32_t W2 = cvt_pk_bf16(pp[6], pp[7]);
      asm volatile("v_permlane32_swap_b32 %0, %1" : "+v"(X), "+v"(Y));
      asm volatile("v_permlane32_swap_b32 %0, %1" : "+v"(Z), "+v"(W2));
      union { uint32_t u[4]; bf16x8 v; } pu;
      pu.u[0] = X; pu.u[1] = Z; pu.u[2] = Y; pu.u[3] = W2;
      pa[jj] = pu.v;
    }

    __builtin_amdgcn_s_setprio(1);
#pragma unroll
    for (int dd = 0; dd < 2; dd++)
#pragma unroll
      for (int jj = 0; jj < 2; jj++)
        oacc[dd] = mfma32(pa[jj], vf[dd * 2 + jj], oacc[dd]);
    __builtin_amdgcn_s_setprio(0);
  };

  // prologue: stage tiles 0..2 into slots 0..2 (12 gld16/wave)
  stage(0, 0);
  stage(1, 1);
  stage(2, 2);
  asm volatile("s_waitcnt vmcnt(8)" ::: "memory");  // tile 0 proven (mine)
  __builtin_amdgcn_s_barrier();

  for (int su = 0; su < 32; ++su) {
    int sn = su + 3;
    if (sn > 31) sn = 31;  // clamped dummy keeps vmcnt cadence; target slot
    stage((su + 3) & 3, sn);  // consumed at su-1, one barrier ago -> safe

    const uint16_t* base = slotbase(su & 3);
    bf16x8 kf[4];
#pragma unroll
    for (int m = 0; m < 4; m++) kf[m] = *(const bf16x8*)(base + m * 512 + l * 8);
    f32x16 Ta = qk(kf, qfA);
    f32x16 Tb = qk(kf, qfB);
    bf16x8 vf[4];
#pragma unroll
    for (int i = 0; i < 4; i++) vf[i] = *(const bf16x8*)(base + (4 + i) * 512 + l * 8);
    finish(Ta, vf, oaccA, lA);
    finish(Tb, vf, oaccB, lB);

    // counted convoy: proves tile su+1 (mine); su+2/su+3 loads stay in flight
    asm volatile("s_waitcnt vmcnt(8) lgkmcnt(0)" ::: "memory");
    __builtin_amdgcn_s_barrier();
  }

  lA += __shfl_xor(lA, 32);  // full row-sums for this half
  lB += __shfl_xor(lB, 32);

  // drain straggler (dummy) stages before reusing LDS for the combine
  asm volatile("s_waitcnt vmcnt(0)" ::: "memory");
  __syncthreads();

  // --- combine the two kv-halves through LDS (partials are exactly additive) ---
  float* exch = (float*)smem;            // 2 qg x 64 rows x 64 cols f32 = 32 KB
  float* exl = (float*)(smem + 32768);   // 2 qg x 64 f32
  if (half == 1) {
#pragma unroll
    for (int sub = 0; sub < 2; sub++) {
      f32x16* oacc = sub ? oaccB : oaccA;
#pragma unroll
      for (int r = 0; r < 16; r++) {
        int qr = (r & 3) + 8 * (r >> 2) + 4 * hi;
        exch[qg * 4096 + (sub * 32 + qr) * 64 + lr] = oacc[0][r];
        exch[qg * 4096 + (sub * 32 + qr) * 64 + 32 + lr] = oacc[1][r];
      }
    }
    if (hi == 0) {
      exl[qg * 64 + lr] = lA;
      exl[qg * 64 + 32 + lr] = lB;
    }
  }
  __syncthreads();
  if (half == 0) {
    lA += exl[qg * 64 + lr];
    lB += exl[qg * 64 + 32 + lr];
    float invA = 1.0f / lA, invB = 1.0f / lB;
#pragma unroll
    for (int sub = 0; sub < 2; sub++) {
      f32x16* oacc = sub ? oaccB : oaccA;
      float inv = sub ? invB : invA;
#pragma unroll
      for (int r = 0; r < 16; r++) {
        int qr = (r & 3) + 8 * (r >> 2) + 4 * hi;
        float iv = __shfl(inv, qr);
        float o0 = oacc[0][r] + exch[qg * 4096 + (sub * 32 + qr) * 64 + lr];
        float o1 = oacc[1][r] + exch[qg * 4096 + (sub * 32 + qr) * 64 + 32 + lr];
        float* orow =
            out + (uint64_t)(b * 2048 + qrow0 + sub * 32 + qr) * 1024 + h * 64 + lr;
        orow[0] = o0 * iv;
        orow[32] = o1 * iv;
      }
    }
  }
}

// ---------- launcher ----------
extern "C" void kernel_launch(void* const* d_in, const int* in_sizes, int n_in,
                              void* d_out, int out_size, void* d_ws, size_t ws_size,
                              hipStream_t stream) {
  const float* x = (const float*)d_in[0];
  const float* wq = (const float*)d_in[1];
  const float* wkv = (const float*)d_in[2];
  const float* kscale = (const float*)d_in[3];
  float* out = (float*)d_out;
  char* ws = (char*)d_ws;
  uint16_t* xb = (uint16_t*)(ws);                     // 8 MB  [4096][1024] bf16
  uint16_t* wt = (uint16_t*)(ws + (8ull << 20));      // 3 MB  [1536][1024] bf16
  uint16_t* q_ws = (uint16_t*)(ws + (11ull << 20));   // 8 MB  [2][16][2048][64]
  uint16_t* kf_ws = (uint16_t*)(ws + (19ull << 20));  // 2 MB  K fragments
  uint16_t* vf_ws = (uint16_t*)(ws + (21ull << 20));  // 2 MB  V fragments

  // allow 64 KB dynamic LDS for the attention kernel
  static bool attr_set = false;
  if (!attr_set) {
    (void)hipFuncSetAttribute((const void*)k_attn,
                              hipFuncAttributeMaxDynamicSharedMemorySize, 65536);
    attr_set = true;
  }

  k_convert<<<2432, 256, 0, stream>>>(x, wq, wkv, xb, wt);
  k_proj_gemm<<<768, 256, 0, stream>>>(xb, wt, kscale, q_ws, kf_ws, vf_ws);
  k_attn<<<512, 256, 65536, stream>>>(q_ws, kf_ws, vf_ws, out);
}

// Round 18
// 74.794 us; speedup vs baseline: 2.3227x; 2.3227x over previous
//
#include <hip/hip_runtime.h>
#include <stdint.h>
#include <math.h>

// ---------- types ----------
typedef __attribute__((ext_vector_type(8))) __bf16 bf16x8;
typedef __attribute__((ext_vector_type(4))) float f32x4;
typedef __attribute__((ext_vector_type(16))) float f32x16;

__device__ __forceinline__ uint32_t f32_to_bf16_rne(float f) {
  union { float f; uint32_t u; } v; v.f = f;
  return (v.u + 0x7FFFu + ((v.u >> 16) & 1u)) >> 16;
}

__device__ __forceinline__ uint32_t cvt_pk_bf16(float lo, float hi) {
  uint32_t r;
  asm("v_cvt_pk_bf16_f32 %0, %1, %2" : "=v"(r) : "v"(lo), "v"(hi));
  return r;
}

__device__ __forceinline__ void gld16(void* lds, const void* g) {
  __builtin_amdgcn_global_load_lds(
      (__attribute__((address_space(1))) void*)(g),
      (__attribute__((address_space(3))) void*)(lds), 16, 0, 0);
}

__device__ __forceinline__ f32x4 mfma16(bf16x8 a, bf16x8 b, f32x4 c) {
  return __builtin_amdgcn_mfma_f32_16x16x32_bf16(a, b, c, 0, 0, 0);
}
__device__ __forceinline__ f32x16 mfma32(bf16x8 a, bf16x8 b, f32x16 c) {
  return __builtin_amdgcn_mfma_f32_32x32x16_bf16(a, b, c, 0, 0, 0);
}

#define LOG2E 1.44269504088896340736f

// ---------- kernel 1: fused converts (x fp32->bf16 ; W transpose->bf16) ------
__global__ __launch_bounds__(256) void k_convert(const float* __restrict__ x,
                                                 const float* __restrict__ wq,
                                                 const float* __restrict__ wkv,
                                                 uint16_t* __restrict__ xb,
                                                 uint16_t* __restrict__ wt) {
  __shared__ float tile[64][65];
  int blk = blockIdx.x;
  int t = threadIdx.x;
  if (blk < 2048) {  // x: one thread per 8 elements
    int i = blk * 256 + t;
    const float4* xv = (const float4*)x;
    float4 a = xv[2 * i], b2 = xv[2 * i + 1];
    uint32_t w0 = f32_to_bf16_rne(a.x) | (f32_to_bf16_rne(a.y) << 16);
    uint32_t w1 = f32_to_bf16_rne(a.z) | (f32_to_bf16_rne(a.w) << 16);
    uint32_t w2 = f32_to_bf16_rne(b2.x) | (f32_to_bf16_rne(b2.y) << 16);
    uint32_t w3 = f32_to_bf16_rne(b2.z) | (f32_to_bf16_rne(b2.w) << 16);
    ((uint4*)xb)[i] = make_uint4(w0, w1, w2, w3);
  } else {  // W: tiled transpose into Wt[c][k]
    int blk2 = blk - 2048;
    int c0 = (blk2 % 24) * 64, k0 = (blk2 / 24) * 64;
    int col = t & 63, rq = t >> 6;
#pragma unroll
    for (int rr = 0; rr < 16; rr++) {
      int r = rr * 4 + rq;
      int c = c0 + col;
      float v = (c < 1024) ? wq[(uint64_t)(k0 + r) * 1024 + c]
                           : wkv[(uint64_t)(k0 + r) * 512 + (c - 1024)];
      tile[r][col] = v;
    }
    __syncthreads();
#pragma unroll
    for (int rr = 0; rr < 16; rr++) {
      int a = rr * 4 + rq;  // output row (c-local)
      wt[(uint64_t)(c0 + a) * 1024 + k0 + col] = (uint16_t)f32_to_bf16_rne(tile[col][a]);
    }
  }
}

// ---------- kernel 2: projection GEMM, BK=64 ring-3, XCD row-panel pinned ----
// 128x64 tile, 768 blocks. Remap: xcd = id%8 owns m-panels [xcd*512,+512) ->
// each XCD's working set = 4 A-panels (1 MB) + B (3 MB) = its 4 MB L2.
// Per K-step: stage(t+2) -> readFrags(t) [proven LAST iter] -> MFMA(t) ->
// vmcnt(6)+lgkmcnt(0)+barrier (compute before the convoy wait).
// Epilogue: q row-major, K/V in SUBTILE-LINEAR fragment order:
//  K frag g = gsu*4 + m    : K[kv=32*gsu + lrr][d=16m + 8hh + el]
//  V frag g = gsu*4+dd*2+jj: V[kv=32*gsu + 16jj + 8hh + el][d=32dd + lrr]
__global__ __launch_bounds__(256, 2) void k_proj_gemm(
    const uint16_t* __restrict__ xb, const uint16_t* __restrict__ wt,
    const float* __restrict__ kscale, uint16_t* __restrict__ q_ws,
    uint16_t* __restrict__ kf_ws, uint16_t* __restrict__ vf_ws) {
  __shared__ __align__(16) uint16_t ring[3][12288];  // slot: A 8192 u16 + B 4096 u16
  int t = threadIdx.x;
  int w = t >> 6, l = t & 63;
  int lq = l & 15, lg = l >> 4;
  // XCD-pinned remap: id%8 = XCD; XCD x computes m-rows [x*512, x*512+512)
  int id = blockIdx.x;
  int xcd = id & 7, idx = id >> 3;        // idx 0..95
  int rrp = idx & 3, cc = idx >> 2;       // 4 row-panels x 24 col-tiles
  int m0 = (xcd * 4 + rrp) * 128, n0 = cc * 64;
  int wr = w >> 1, wc = w & 1;  // 2x2 waves: 64 rows x 32 cols each
  f32x4 acc[4][2] = {};

  auto stage = [&](int slot, int k0) {
#pragma unroll
    for (int j = 0; j < 4; j++) {  // A: 128 rows x 64 cols = 1024 chunks of 16B
      int c = j * 256 + t;
      int r = c >> 3, s = c & 7;
      int sl = s ^ (r & 7);
      gld16((char*)&ring[slot][0] + c * 16,
            xb + (uint64_t)(m0 + r) * 1024 + k0 + sl * 8);
    }
#pragma unroll
    for (int j = 0; j < 2; j++) {  // B: 64 rows x 64 cols = 512 chunks
      int c = j * 256 + t;
      int r = c >> 3, s = c & 7;
      int sl = s ^ (r & 7);
      gld16((char*)&ring[slot][8192] + c * 16,
            wt + (uint64_t)(n0 + r) * 1024 + k0 + sl * 8);
    }
  };

  stage(0, 0);
  stage(1, 64);
  asm volatile("s_waitcnt vmcnt(6)" ::: "memory");  // slot 0 proven
  __builtin_amdgcn_s_barrier();

  for (int it = 0; it < 16; ++it) {
    // stage(t+2); dummies at the tail re-stage byte-identical data
    int tn = it + 2;
    int kn = (tn < 16) ? tn * 64 : (tn - 3) * 64;
    stage(tn % 3, kn);

    // read frags of slot it (proven by LAST iteration's vmcnt+barrier)
    const uint16_t* As = &ring[it % 3][0];
    const uint16_t* Bs = &ring[it % 3][8192];
    bf16x8 af[2][4], bfr[2][2];
#pragma unroll
    for (int kk = 0; kk < 2; kk++) {
#pragma unroll
      for (int m = 0; m < 4; m++) {
        int r = wr * 64 + m * 16 + lq;
        int sl = (kk * 4 + lg) ^ (r & 7);
        af[kk][m] = *(const bf16x8*)(As + r * 64 + sl * 8);
      }
#pragma unroll
      for (int n = 0; n < 2; n++) {
        int r = wc * 32 + n * 16 + lq;
        int sl = (kk * 4 + lg) ^ (r & 7);
        bfr[kk][n] = *(const bf16x8*)(Bs + r * 64 + sl * 8);
      }
    }
    __builtin_amdgcn_s_setprio(1);
#pragma unroll
    for (int kk = 0; kk < 2; kk++)
#pragma unroll
      for (int m = 0; m < 4; m++)
#pragma unroll
        for (int n = 0; n < 2; n++)
          acc[m][n] = mfma16(af[kk][m], bfr[kk][n], acc[m][n]);
    __builtin_amdgcn_s_setprio(0);

    // convoy AFTER compute: proves slot it+1 for next iter; lgkm drains the
    // ds_reads of slot it before anyone re-stages it (slot (it+3)%3 == it%3).
    asm volatile("s_waitcnt vmcnt(6) lgkmcnt(0)" ::: "memory");
    __builtin_amdgcn_s_barrier();
  }

#pragma unroll
  for (int m = 0; m < 4; m++)
#pragma unroll
    for (int n = 0; n < 2; n++)
#pragma unroll
      for (int jj = 0; jj < 4; jj++) {
        int row = m0 + wr * 64 + m * 16 + 4 * lg + jj;  // b*2048+n
        int col = n0 + wc * 32 + n * 16 + lq;           // 0..1535
        float val = acc[m][n][jj];
        int b = row >> 11, nn = row & 2047;
        if (col < 1024) {
          // fold qk-norm scale, 1/sqrt(64), and log2(e) (for exp2 softmax) into q
          val *= kscale[col] * 0.125f * LOG2E;
          q_ws[((uint64_t)((b * 16 + (col >> 6)) * 2048 + nn)) * 64 + (col & 63)] =
              (uint16_t)f32_to_bf16_rne(val);
        } else if (col < 1280) {
          int kvh = (col - 1024) >> 6;
          int d = col & 63;
          int gsu = nn >> 5, lrr = nn & 31;
          int mm = d >> 4, hh = (d >> 3) & 1, el = d & 7;
          kf_ws[(uint64_t)(b * 4 + kvh) * 131072 +
                (uint64_t)((((gsu * 4 + mm) * 64) + hh * 32 + lrr) * 8 + el)] =
              (uint16_t)f32_to_bf16_rne(val);
        } else {
          int kvh = (col - 1280) >> 6;
          int d = col & 63;
          int gsu = nn >> 5, jj2 = (nn >> 4) & 1, hh = (nn >> 3) & 1, el = nn & 7;
          int dd = d >> 5, lrr = d & 31;
          vf_ws[(uint64_t)(b * 4 + kvh) * 131072 +
                (uint64_t)((((gsu * 4 + dd * 2 + jj2) * 64) + hh * 32 + lrr) * 8 + el)] =
              (uint16_t)f32_to_bf16_rne(val);
        }
      }
}

// ---------- kernel 3: flash attention, anti-phase wave classes (R11/R14 best) --
// 256 blocks (1/CU) x 512 thr: 8 waves = 4 q-groups (64 rows) x 2 kv-halves.
// Window = 2 kv-tiles, ring-8 x 16 KB (stage a+6,a+7 -> slots consumed 2
// windows ago), vmcnt(8)+barrier per window (16 barriers). SIMD i hosts wave i
// (half 0) and wave i+4 (half 1); the halves run DIFFERENT intra-window orders
// (MVMV vs MMVV) so one wave's softmax overlaps the other's MFMA.
// No max-subtraction softmax (log2-domain scores bounded; partials additive).
// NOTE (R17): 1 block/CU lockstep is load-bearing — it keeps the KV stream
// L2-resident; 2 drifting blocks/CU thrashed L2 (FETCH 3.3x, 42->151 us).
__global__ __launch_bounds__(512, 1) void k_attn(const uint16_t* __restrict__ q_ws,
                                                 const uint16_t* __restrict__ kf_ws,
                                                 const uint16_t* __restrict__ vf_ws,
                                                 float* __restrict__ out) {
  extern __shared__ __align__(16) char smem[];  // 128 KB ring-8

  int t = threadIdx.x, w = t >> 6, l = t & 63;
  int lr = l & 31, hi = l >> 5;
  int qg = w & 3, half = w >> 2;
  // XCD-pinned remap: all blocks sharing (b,kvh) land on one XCD (blk%8 = XCD)
  int blk = blockIdx.x;
  int c = blk & 7, j = blk >> 3;
  int b = c >> 2, kvh = c & 3;
  int h = kvh * 4 + (j >> 3), qb = j & 7;

  const uint16_t* Qb = q_ws + (uint64_t)(b * 16 + h) * 2048 * 64;
  const uint16_t* Kb = kf_ws + (uint64_t)(b * 4 + kvh) * 131072;
  const uint16_t* Vb = vf_ws + (uint64_t)(b * 4 + kvh) * 131072;
  int qrow0 = qb * 256 + qg * 64;  // this wave's 64 q-rows

  // Q B-frags for both 32-row subtiles
  bf16x8 qfA[4], qfB[4];
#pragma unroll
  for (int m = 0; m < 4; m++) {
    qfA[m] = *(const bf16x8*)(Qb + (uint64_t)(qrow0 + lr) * 64 + m * 16 + hi * 8);
    qfB[m] = *(const bf16x8*)(Qb + (uint64_t)(qrow0 + 32 + lr) * 64 + m * 16 + hi * 8);
  }

  f32x16 oaccA[2] = {}, oaccB[2] = {};
  float lA = 0.f, lB = 0.f;

  // staging: wave (qg,half) covers 2 frags of its half: qg<2 -> K, qg>=2 -> V
  const uint16_t* SbW = ((qg < 2) ? Kb : Vb) + (uint64_t)half * 65536 +
                        (uint64_t)((qg & 1) * 2) * 512 + l * 8;
  char* dstW = smem + half * 8192 + ((qg < 2) ? 0 : 4096) + (qg & 1) * 2048 + l * 16;

  auto stage = [&](int slot, int sul) {
    char* d = dstW + slot * 16384;
    const uint16_t* s = SbW + (uint64_t)sul * 2048;
    gld16(d, s);
    gld16(d + 1024, s + 512);
  };
  auto slotbase = [&](int slot) {
    return (const uint16_t*)(smem + slot * 16384 + half * 8192);
  };

  auto readK = [&](bf16x8* kf, const uint16_t* base) {
#pragma unroll
    for (int m = 0; m < 4; m++) kf[m] = *(const bf16x8*)(base + m * 512 + l * 8);
  };
  auto readV = [&](bf16x8* vf, const uint16_t* base) {
#pragma unroll
    for (int i = 0; i < 4; i++) vf[i] = *(const bf16x8*)(base + (4 + i) * 512 + l * 8);
  };
  auto qk = [&](const bf16x8* kf, const bf16x8* qf) {
    f32x16 T = {};
    __builtin_amdgcn_s_setprio(1);
#pragma unroll
    for (int m = 0; m < 4; m++) T = mfma32(kf[m], qf[m], T);
    __builtin_amdgcn_s_setprio(0);
    return T;
  };

  // finish one 32-row subtile: softmax (exp2, no max shift), pack, PV
  auto finish = [&](f32x16& Tc, const bf16x8* vf, f32x16* oacc, float& lsum) {
    float p[16];
#pragma unroll
    for (int e = 0; e < 16; e++) p[e] = __builtin_amdgcn_exp2f(Tc[e]);
    float sm0 = ((p[0] + p[1]) + (p[2] + p[3])) + ((p[4] + p[5]) + (p[6] + p[7]));
    float sm1 = ((p[8] + p[9]) + (p[10] + p[11])) + ((p[12] + p[13]) + (p[14] + p[15]));
    lsum += sm0 + sm1;  // cross-half-lane shfl deferred to after the loop

    bf16x8 pa[2];
#pragma unroll
    for (int jj = 0; jj < 2; jj++) {
      const float* pp = p + 8 * jj;
      uint32_t X = cvt_pk_bf16(pp[0], pp[1]);
      uint32_t Z = cvt_pk_bf16(pp[2], pp[3]);
      uint32_t Y = cvt_pk_bf16(pp[4], pp[5]);
      uint32_t W2 = cvt_pk_bf16(pp[6], pp[7]);
      asm volatile("v_permlane32_swap_b32 %0, %1" : "+v"(X), "+v"(Y));
      asm volatile("v_permlane32_swap_b32 %0, %1" : "+v"(Z), "+v"(W2));
      union { uint32_t u[4]; bf16x8 v; } pu;
      pu.u[0] = X; pu.u[1] = Z; pu.u[2] = Y; pu.u[3] = W2;
      pa[jj] = pu.v;
    }

    __builtin_amdgcn_s_setprio(1);
#pragma unroll
    for (int dd = 0; dd < 2; dd++)
#pragma unroll
      for (int jj = 0; jj < 2; jj++)
        oacc[dd] = mfma32(pa[jj], vf[dd * 2 + jj], oacc[dd]);
    __builtin_amdgcn_s_setprio(0);
  };

  // prologue: stage tiles 0..5 into slots 0..5 (12 gld16/wave)
#pragma unroll
  for (int tt = 0; tt < 6; ++tt) stage(tt, tt);
  asm volatile("s_waitcnt vmcnt(4)" ::: "memory");  // tiles 0..3 proven (mine)
  __builtin_amdgcn_s_barrier();

  for (int iv = 0; iv < 16; ++iv) {
    int a = 2 * iv;
    int s0 = a + 6, s1 = a + 7;
    if (s0 > 31) s0 = 31;  // clamped dummies keep vmcnt cadence; target slots
    if (s1 > 31) s1 = 31;  // were consumed >=2 windows ago (barrier-protected)
    stage((a + 6) & 7, s0);
    stage((a + 7) & 7, s1);

    const uint16_t* b0 = slotbase(a & 7);
    const uint16_t* b1 = slotbase((a + 1) & 7);

    if (half == 0) {  // class MVMV
      bf16x8 kf[4], vf[4];
      readK(kf, b0);
      readV(vf, b0);
      f32x16 Ta = qk(kf, qfA);
      f32x16 Tb = qk(kf, qfB);
      finish(Ta, vf, oaccA, lA);
      finish(Tb, vf, oaccB, lB);
      readK(kf, b1);
      readV(vf, b1);
      Ta = qk(kf, qfA);
      Tb = qk(kf, qfB);
      finish(Ta, vf, oaccA, lA);
      finish(Tb, vf, oaccB, lB);
    } else {  // class MMVV
      bf16x8 kf0[4], kf1[4];
      readK(kf0, b0);
      readK(kf1, b1);
      f32x16 T0a = qk(kf0, qfA);
      f32x16 T0b = qk(kf0, qfB);
      f32x16 T1a = qk(kf1, qfA);
      f32x16 T1b = qk(kf1, qfB);
      bf16x8 vf[4];
      readV(vf, b0);
      finish(T0a, vf, oaccA, lA);
      finish(T0b, vf, oaccB, lB);
      readV(vf, b1);
      finish(T1a, vf, oaccA, lA);
      finish(T1b, vf, oaccB, lB);
    }

    asm volatile("s_waitcnt vmcnt(8)" ::: "memory");  // tiles a+2,a+3 proven (mine)
    __builtin_amdgcn_s_barrier();                     // ...and everyone's
  }

  lA += __shfl_xor(lA, 32);  // full row-sums for this half
  lB += __shfl_xor(lB, 32);

  // drain straggler (dummy) stages before reusing LDS for the combine
  asm volatile("s_waitcnt vmcnt(0)" ::: "memory");
  __syncthreads();

  // --- combine the two kv-halves through LDS (partials are exactly additive) ---
  float* exch = (float*)smem;            // 4 qg x 64 rows x 64 cols f32 = 64 KB
  float* exl = (float*)(smem + 65536);   // 4 qg x 64 f32
  if (half == 1) {
#pragma unroll
    for (int sub = 0; sub < 2; sub++) {
      f32x16* oacc = sub ? oaccB : oaccA;
#pragma unroll
      for (int r = 0; r < 16; r++) {
        int qr = (r & 3) + 8 * (r >> 2) + 4 * hi;
        exch[qg * 4096 + (sub * 32 + qr) * 64 + lr] = oacc[0][r];
        exch[qg * 4096 + (sub * 32 + qr) * 64 + 32 + lr] = oacc[1][r];
      }
    }
    if (hi == 0) {
      exl[qg * 64 + lr] = lA;
      exl[qg * 64 + 32 + lr] = lB;
    }
  }
  __syncthreads();
  if (half == 0) {
    lA += exl[qg * 64 + lr];
    lB += exl[qg * 64 + 32 + lr];
    float invA = 1.0f / lA, invB = 1.0f / lB;
#pragma unroll
    for (int sub = 0; sub < 2; sub++) {
      f32x16* oacc = sub ? oaccB : oaccA;
      float inv = sub ? invB : invA;
#pragma unroll
      for (int r = 0; r < 16; r++) {
        int qr = (r & 3) + 8 * (r >> 2) + 4 * hi;
        float iv = __shfl(inv, qr);
        float o0 = oacc[0][r] + exch[qg * 4096 + (sub * 32 + qr) * 64 + lr];
        float o1 = oacc[1][r] + exch[qg * 4096 + (sub * 32 + qr) * 64 + 32 + lr];
        float* orow =
            out + (uint64_t)(b * 2048 + qrow0 + sub * 32 + qr) * 1024 + h * 64 + lr;
        orow[0] = o0 * iv;
        orow[32] = o1 * iv;
      }
    }
  }
}

// ---------- launcher ----------
extern "C" void kernel_launch(void* const* d_in, const int* in_sizes, int n_in,
                              void* d_out, int out_size, void* d_ws, size_t ws_size,
                              hipStream_t stream) {
  const float* x = (const float*)d_in[0];
  const float* wq = (const float*)d_in[1];
  const float* wkv = (const float*)d_in[2];
  const float* kscale = (const float*)d_in[3];
  float* out = (float*)d_out;
  char* ws = (char*)d_ws;
  uint16_t* xb = (uint16_t*)(ws);                     // 8 MB  [4096][1024] bf16
  uint16_t* wt = (uint16_t*)(ws + (8ull << 20));      // 3 MB  [1536][1024] bf16
  uint16_t* q_ws = (uint16_t*)(ws + (11ull << 20));   // 8 MB  [2][16][2048][64]
  uint16_t* kf_ws = (uint16_t*)(ws + (19ull << 20));  // 2 MB  K fragments
  uint16_t* vf_ws = (uint16_t*)(ws + (21ull << 20));  // 2 MB  V fragments

  // allow 128 KB dynamic LDS for the attention kernel
  static bool attr_set = false;
  if (!attr_set) {
    (void)hipFuncSetAttribute((const void*)k_attn,
                              hipFuncAttributeMaxDynamicSharedMemorySize, 131072);
    attr_set = true;
  }

  k_convert<<<2432, 256, 0, stream>>>(x, wq, wkv, xb, wt);
  k_proj_gemm<<<768, 256, 0, stream>>>(xb, wt, kscale, q_ws, kf_ws, vf_ws);
  k_attn<<<256, 512, 131072, stream>>>(q_ws, kf_ws, vf_ws, out);
}

// Round 19
// 69.604 us; speedup vs baseline: 2.4959x; 1.0746x over previous
//
#include <hip/hip_runtime.h>
#include <stdint.h>
#include <math.h>

// ---------- types ----------
typedef __attribute__((ext_vector_type(8))) __bf16 bf16x8;
typedef __attribute__((ext_vector_type(4))) float f32x4;
typedef __attribute__((ext_vector_type(16))) float f32x16;

__device__ __forceinline__ uint32_t f32_to_bf16_rne(float f) {
  union { float f; uint32_t u; } v; v.f = f;
  return (v.u + 0x7FFFu + ((v.u >> 16) & 1u)) >> 16;
}

__device__ __forceinline__ uint32_t cvt_pk_bf16(float lo, float hi) {
  uint32_t r;
  asm("v_cvt_pk_bf16_f32 %0, %1, %2" : "=v"(r) : "v"(lo), "v"(hi));
  return r;
}

__device__ __forceinline__ void gld16(void* lds, const void* g) {
  __builtin_amdgcn_global_load_lds(
      (__attribute__((address_space(1))) void*)(g),
      (__attribute__((address_space(3))) void*)(lds), 16, 0, 0);
}

__device__ __forceinline__ f32x4 mfma16(bf16x8 a, bf16x8 b, f32x4 c) {
  return __builtin_amdgcn_mfma_f32_16x16x32_bf16(a, b, c, 0, 0, 0);
}
__device__ __forceinline__ f32x16 mfma32(bf16x8 a, bf16x8 b, f32x16 c) {
  return __builtin_amdgcn_mfma_f32_32x32x16_bf16(a, b, c, 0, 0, 0);
}

#define LOG2E 1.44269504088896340736f

// ---------- kernel 1: fused converts (x fp32->bf16 ; W transpose->bf16) ------
__global__ __launch_bounds__(256) void k_convert(const float* __restrict__ x,
                                                 const float* __restrict__ wq,
                                                 const float* __restrict__ wkv,
                                                 uint16_t* __restrict__ xb,
                                                 uint16_t* __restrict__ wt) {
  __shared__ float tile[64][65];
  int blk = blockIdx.x;
  int t = threadIdx.x;
  if (blk < 2048) {  // x: one thread per 8 elements
    int i = blk * 256 + t;
    const float4* xv = (const float4*)x;
    float4 a = xv[2 * i], b2 = xv[2 * i + 1];
    uint32_t w0 = f32_to_bf16_rne(a.x) | (f32_to_bf16_rne(a.y) << 16);
    uint32_t w1 = f32_to_bf16_rne(a.z) | (f32_to_bf16_rne(a.w) << 16);
    uint32_t w2 = f32_to_bf16_rne(b2.x) | (f32_to_bf16_rne(b2.y) << 16);
    uint32_t w3 = f32_to_bf16_rne(b2.z) | (f32_to_bf16_rne(b2.w) << 16);
    ((uint4*)xb)[i] = make_uint4(w0, w1, w2, w3);
  } else {  // W: tiled transpose into Wt[c][k]
    int blk2 = blk - 2048;
    int c0 = (blk2 % 24) * 64, k0 = (blk2 / 24) * 64;
    int col = t & 63, rq = t >> 6;
#pragma unroll
    for (int rr = 0; rr < 16; rr++) {
      int r = rr * 4 + rq;
      int c = c0 + col;
      float v = (c < 1024) ? wq[(uint64_t)(k0 + r) * 1024 + c]
                           : wkv[(uint64_t)(k0 + r) * 512 + (c - 1024)];
      tile[r][col] = v;
    }
    __syncthreads();
#pragma unroll
    for (int rr = 0; rr < 16; rr++) {
      int a = rr * 4 + rq;  // output row (c-local)
      wt[(uint64_t)(c0 + a) * 1024 + k0 + col] = (uint16_t)f32_to_bf16_rne(tile[col][a]);
    }
  }
}

// ---------- kernel 2: projection GEMM, BK=64 ring-2, 3 blocks/CU ----------
// 128x64 tile, 768 blocks, ALL co-resident (48 KB LDS -> 3/CU; zero tail).
// m97/m114 regime: stage(t+1) -> frags(t)+MFMA(t) -> vmcnt(0)+lgkm+barrier;
// the full drain is covered by the other two resident blocks' waves.
// XCD pinning: id%8 = XCD owns m-panels [xcd*512,+512) -> A (1 MB) + B (3 MB)
// = its 4 MB L2. Epilogue: q row-major, K/V in SUBTILE-LINEAR fragment order:
//  K frag g = gsu*4 + m    : K[kv=32*gsu + lrr][d=16m + 8hh + el]
//  V frag g = gsu*4+dd*2+jj: V[kv=32*gsu + 16jj + 8hh + el][d=32dd + lrr]
__global__ __launch_bounds__(256, 3) void k_proj_gemm(
    const uint16_t* __restrict__ xb, const uint16_t* __restrict__ wt,
    const float* __restrict__ kscale, uint16_t* __restrict__ q_ws,
    uint16_t* __restrict__ kf_ws, uint16_t* __restrict__ vf_ws) {
  __shared__ __align__(16) uint16_t ring[2][12288];  // slot: A 8192 u16 + B 4096 u16
  int t = threadIdx.x;
  int w = t >> 6, l = t & 63;
  int lq = l & 15, lg = l >> 4;
  // XCD-pinned remap: id%8 = XCD; XCD x computes m-rows [x*512, x*512+512)
  int id = blockIdx.x;
  int xcd = id & 7, idx = id >> 3;        // idx 0..95
  int rrp = idx & 3, cc = idx >> 2;       // 4 row-panels x 24 col-tiles
  int m0 = (xcd * 4 + rrp) * 128, n0 = cc * 64;
  int wr = w >> 1, wc = w & 1;  // 2x2 waves: 64 rows x 32 cols each
  f32x4 acc[4][2] = {};

  auto stage = [&](int slot, int k0) {
#pragma unroll
    for (int j = 0; j < 4; j++) {  // A: 128 rows x 64 cols = 1024 chunks of 16B
      int c = j * 256 + t;
      int r = c >> 3, s = c & 7;
      int sl = s ^ (r & 7);
      gld16((char*)&ring[slot][0] + c * 16,
            xb + (uint64_t)(m0 + r) * 1024 + k0 + sl * 8);
    }
#pragma unroll
    for (int j = 0; j < 2; j++) {  // B: 64 rows x 64 cols = 512 chunks
      int c = j * 256 + t;
      int r = c >> 3, s = c & 7;
      int sl = s ^ (r & 7);
      gld16((char*)&ring[slot][8192] + c * 16,
            wt + (uint64_t)(n0 + r) * 1024 + k0 + sl * 8);
    }
  };

  stage(0, 0);
  asm volatile("s_waitcnt vmcnt(0)" ::: "memory");
  __builtin_amdgcn_s_barrier();

  int cur = 0;
  for (int it = 0; it < 16; ++it) {
    // stage next K-step into the other slot (its ds_reads drained last iter)
    if (it + 1 < 16) stage(cur ^ 1, (it + 1) * 64);

    // read frags of slot cur (proven by last iteration's drain+barrier)
    const uint16_t* As = &ring[cur][0];
    const uint16_t* Bs = &ring[cur][8192];
    bf16x8 af[2][4], bfr[2][2];
#pragma unroll
    for (int kk = 0; kk < 2; kk++) {
#pragma unroll
      for (int m = 0; m < 4; m++) {
        int r = wr * 64 + m * 16 + lq;
        int sl = (kk * 4 + lg) ^ (r & 7);
        af[kk][m] = *(const bf16x8*)(As + r * 64 + sl * 8);
      }
#pragma unroll
      for (int n = 0; n < 2; n++) {
        int r = wc * 32 + n * 16 + lq;
        int sl = (kk * 4 + lg) ^ (r & 7);
        bfr[kk][n] = *(const bf16x8*)(Bs + r * 64 + sl * 8);
      }
    }
    __builtin_amdgcn_s_setprio(1);
#pragma unroll
    for (int kk = 0; kk < 2; kk++)
#pragma unroll
      for (int m = 0; m < 4; m++)
#pragma unroll
        for (int n = 0; n < 2; n++)
          acc[m][n] = mfma16(af[kk][m], bfr[kk][n], acc[m][n]);
    __builtin_amdgcn_s_setprio(0);

    // full drain + barrier: next tile ready, this slot's reads complete.
    // The stall is covered by the other two co-resident blocks (m114).
    asm volatile("s_waitcnt vmcnt(0) lgkmcnt(0)" ::: "memory");
    __builtin_amdgcn_s_barrier();
    cur ^= 1;
  }

#pragma unroll
  for (int m = 0; m < 4; m++)
#pragma unroll
    for (int n = 0; n < 2; n++)
#pragma unroll
      for (int jj = 0; jj < 4; jj++) {
        int row = m0 + wr * 64 + m * 16 + 4 * lg + jj;  // b*2048+n
        int col = n0 + wc * 32 + n * 16 + lq;           // 0..1535
        float val = acc[m][n][jj];
        int b = row >> 11, nn = row & 2047;
        if (col < 1024) {
          // fold qk-norm scale, 1/sqrt(64), and log2(e) (for exp2 softmax) into q
          val *= kscale[col] * 0.125f * LOG2E;
          q_ws[((uint64_t)((b * 16 + (col >> 6)) * 2048 + nn)) * 64 + (col & 63)] =
              (uint16_t)f32_to_bf16_rne(val);
        } else if (col < 1280) {
          int kvh = (col - 1024) >> 6;
          int d = col & 63;
          int gsu = nn >> 5, lrr = nn & 31;
          int mm = d >> 4, hh = (d >> 3) & 1, el = d & 7;
          kf_ws[(uint64_t)(b * 4 + kvh) * 131072 +
                (uint64_t)((((gsu * 4 + mm) * 64) + hh * 32 + lrr) * 8 + el)] =
              (uint16_t)f32_to_bf16_rne(val);
        } else {
          int kvh = (col - 1280) >> 6;
          int d = col & 63;
          int gsu = nn >> 5, jj2 = (nn >> 4) & 1, hh = (nn >> 3) & 1, el = nn & 7;
          int dd = d >> 5, lrr = d & 31;
          vf_ws[(uint64_t)(b * 4 + kvh) * 131072 +
                (uint64_t)((((gsu * 4 + dd * 2 + jj2) * 64) + hh * 32 + lrr) * 8 + el)] =
              (uint16_t)f32_to_bf16_rne(val);
        }
      }
}

// ---------- kernel 3: flash attention, anti-phase wave classes (R11/R14 best) --
// 256 blocks (1/CU) x 512 thr: 8 waves = 4 q-groups (64 rows) x 2 kv-halves.
// Window = 2 kv-tiles, ring-8 x 16 KB (stage a+6,a+7 -> slots consumed 2
// windows ago), vmcnt(8)+barrier per window (16 barriers). SIMD i hosts wave i
// (half 0) and wave i+4 (half 1); the halves run DIFFERENT intra-window orders
// (MVMV vs MMVV) so one wave's softmax overlaps the other's MFMA.
// No max-subtraction softmax (log2-domain scores bounded; partials additive).
// NOTE (R17): 1 block/CU lockstep is load-bearing — it keeps the KV stream
// L2-resident; 2 drifting blocks/CU thrashed L2 (FETCH 3.3x, 42->151 us).
__global__ __launch_bounds__(512, 1) void k_attn(const uint16_t* __restrict__ q_ws,
                                                 const uint16_t* __restrict__ kf_ws,
                                                 const uint16_t* __restrict__ vf_ws,
                                                 float* __restrict__ out) {
  extern __shared__ __align__(16) char smem[];  // 128 KB ring-8

  int t = threadIdx.x, w = t >> 6, l = t & 63;
  int lr = l & 31, hi = l >> 5;
  int qg = w & 3, half = w >> 2;
  // XCD-pinned remap: all blocks sharing (b,kvh) land on one XCD (blk%8 = XCD)
  int blk = blockIdx.x;
  int c = blk & 7, j = blk >> 3;
  int b = c >> 2, kvh = c & 3;
  int h = kvh * 4 + (j >> 3), qb = j & 7;

  const uint16_t* Qb = q_ws + (uint64_t)(b * 16 + h) * 2048 * 64;
  const uint16_t* Kb = kf_ws + (uint64_t)(b * 4 + kvh) * 131072;
  const uint16_t* Vb = vf_ws + (uint64_t)(b * 4 + kvh) * 131072;
  int qrow0 = qb * 256 + qg * 64;  // this wave's 64 q-rows

  // Q B-frags for both 32-row subtiles
  bf16x8 qfA[4], qfB[4];
#pragma unroll
  for (int m = 0; m < 4; m++) {
    qfA[m] = *(const bf16x8*)(Qb + (uint64_t)(qrow0 + lr) * 64 + m * 16 + hi * 8);
    qfB[m] = *(const bf16x8*)(Qb + (uint64_t)(qrow0 + 32 + lr) * 64 + m * 16 + hi * 8);
  }

  f32x16 oaccA[2] = {}, oaccB[2] = {};
  float lA = 0.f, lB = 0.f;

  // staging: wave (qg,half) covers 2 frags of its half: qg<2 -> K, qg>=2 -> V
  const uint16_t* SbW = ((qg < 2) ? Kb : Vb) + (uint64_t)half * 65536 +
                        (uint64_t)((qg & 1) * 2) * 512 + l * 8;
  char* dstW = smem + half * 8192 + ((qg < 2) ? 0 : 4096) + (qg & 1) * 2048 + l * 16;

  auto stage = [&](int slot, int sul) {
    char* d = dstW + slot * 16384;
    const uint16_t* s = SbW + (uint64_t)sul * 2048;
    gld16(d, s);
    gld16(d + 1024, s + 512);
  };
  auto slotbase = [&](int slot) {
    return (const uint16_t*)(smem + slot * 16384 + half * 8192);
  };

  auto readK = [&](bf16x8* kf, const uint16_t* base) {
#pragma unroll
    for (int m = 0; m < 4; m++) kf[m] = *(const bf16x8*)(base + m * 512 + l * 8);
  };
  auto readV = [&](bf16x8* vf, const uint16_t* base) {
#pragma unroll
    for (int i = 0; i < 4; i++) vf[i] = *(const bf16x8*)(base + (4 + i) * 512 + l * 8);
  };
  auto qk = [&](const bf16x8* kf, const bf16x8* qf) {
    f32x16 T = {};
    __builtin_amdgcn_s_setprio(1);
#pragma unroll
    for (int m = 0; m < 4; m++) T = mfma32(kf[m], qf[m], T);
    __builtin_amdgcn_s_setprio(0);
    return T;
  };

  // finish one 32-row subtile: softmax (exp2, no max shift), pack, PV
  auto finish = [&](f32x16& Tc, const bf16x8* vf, f32x16* oacc, float& lsum) {
    float p[16];
#pragma unroll
    for (int e = 0; e < 16; e++) p[e] = __builtin_amdgcn_exp2f(Tc[e]);
    float sm0 = ((p[0] + p[1]) + (p[2] + p[3])) + ((p[4] + p[5]) + (p[6] + p[7]));
    float sm1 = ((p[8] + p[9]) + (p[10] + p[11])) + ((p[12] + p[13]) + (p[14] + p[15]));
    lsum += sm0 + sm1;  // cross-half-lane shfl deferred to after the loop

    bf16x8 pa[2];
#pragma unroll
    for (int jj = 0; jj < 2; jj++) {
      const float* pp = p + 8 * jj;
      uint32_t X = cvt_pk_bf16(pp[0], pp[1]);
      uint32_t Z = cvt_pk_bf16(pp[2], pp[3]);
      uint32_t Y = cvt_pk_bf16(pp[4], pp[5]);
      uint32_t W2 = cvt_pk_bf16(pp[6], pp[7]);
      asm volatile("v_permlane32_swap_b32 %0, %1" : "+v"(X), "+v"(Y));
      asm volatile("v_permlane32_swap_b32 %0, %1" : "+v"(Z), "+v"(W2));
      union { uint32_t u[4]; bf16x8 v; } pu;
      pu.u[0] = X; pu.u[1] = Z; pu.u[2] = Y; pu.u[3] = W2;
      pa[jj] = pu.v;
    }

    __builtin_amdgcn_s_setprio(1);
#pragma unroll
    for (int dd = 0; dd < 2; dd++)
#pragma unroll
      for (int jj = 0; jj < 2; jj++)
        oacc[dd] = mfma32(pa[jj], vf[dd * 2 + jj], oacc[dd]);
    __builtin_amdgcn_s_setprio(0);
  };

  // prologue: stage tiles 0..5 into slots 0..5 (12 gld16/wave)
#pragma unroll
  for (int tt = 0; tt < 6; ++tt) stage(tt, tt);
  asm volatile("s_waitcnt vmcnt(4)" ::: "memory");  // tiles 0..3 proven (mine)
  __builtin_amdgcn_s_barrier();

  for (int iv = 0; iv < 16; ++iv) {
    int a = 2 * iv;
    int s0 = a + 6, s1 = a + 7;
    if (s0 > 31) s0 = 31;  // clamped dummies keep vmcnt cadence; target slots
    if (s1 > 31) s1 = 31;  // were consumed >=2 windows ago (barrier-protected)
    stage((a + 6) & 7, s0);
    stage((a + 7) & 7, s1);

    const uint16_t* b0 = slotbase(a & 7);
    const uint16_t* b1 = slotbase((a + 1) & 7);

    if (half == 0) {  // class MVMV
      bf16x8 kf[4], vf[4];
      readK(kf, b0);
      readV(vf, b0);
      f32x16 Ta = qk(kf, qfA);
      f32x16 Tb = qk(kf, qfB);
      finish(Ta, vf, oaccA, lA);
      finish(Tb, vf, oaccB, lB);
      readK(kf, b1);
      readV(vf, b1);
      Ta = qk(kf, qfA);
      Tb = qk(kf, qfB);
      finish(Ta, vf, oaccA, lA);
      finish(Tb, vf, oaccB, lB);
    } else {  // class MMVV
      bf16x8 kf0[4], kf1[4];
      readK(kf0, b0);
      readK(kf1, b1);
      f32x16 T0a = qk(kf0, qfA);
      f32x16 T0b = qk(kf0, qfB);
      f32x16 T1a = qk(kf1, qfA);
      f32x16 T1b = qk(kf1, qfB);
      bf16x8 vf[4];
      readV(vf, b0);
      finish(T0a, vf, oaccA, lA);
      finish(T0b, vf, oaccB, lB);
      readV(vf, b1);
      finish(T1a, vf, oaccA, lA);
      finish(T1b, vf, oaccB, lB);
    }

    asm volatile("s_waitcnt vmcnt(8)" ::: "memory");  // tiles a+2,a+3 proven (mine)
    __builtin_amdgcn_s_barrier();                     // ...and everyone's
  }

  lA += __shfl_xor(lA, 32);  // full row-sums for this half
  lB += __shfl_xor(lB, 32);

  // drain straggler (dummy) stages before reusing LDS for the combine
  asm volatile("s_waitcnt vmcnt(0)" ::: "memory");
  __syncthreads();

  // --- combine the two kv-halves through LDS (partials are exactly additive) ---
  float* exch = (float*)smem;            // 4 qg x 64 rows x 64 cols f32 = 64 KB
  float* exl = (float*)(smem + 65536);   // 4 qg x 64 f32
  if (half == 1) {
#pragma unroll
    for (int sub = 0; sub < 2; sub++) {
      f32x16* oacc = sub ? oaccB : oaccA;
#pragma unroll
      for (int r = 0; r < 16; r++) {
        int qr = (r & 3) + 8 * (r >> 2) + 4 * hi;
        exch[qg * 4096 + (sub * 32 + qr) * 64 + lr] = oacc[0][r];
        exch[qg * 4096 + (sub * 32 + qr) * 64 + 32 + lr] = oacc[1][r];
      }
    }
    if (hi == 0) {
      exl[qg * 64 + lr] = lA;
      exl[qg * 64 + 32 + lr] = lB;
    }
  }
  __syncthreads();
  if (half == 0) {
    lA += exl[qg * 64 + lr];
    lB += exl[qg * 64 + 32 + lr];
    float invA = 1.0f / lA, invB = 1.0f / lB;
#pragma unroll
    for (int sub = 0; sub < 2; sub++) {
      f32x16* oacc = sub ? oaccB : oaccA;
      float inv = sub ? invB : invA;
#pragma unroll
      for (int r = 0; r < 16; r++) {
        int qr = (r & 3) + 8 * (r >> 2) + 4 * hi;
        float iv = __shfl(inv, qr);
        float o0 = oacc[0][r] + exch[qg * 4096 + (sub * 32 + qr) * 64 + lr];
        float o1 = oacc[1][r] + exch[qg * 4096 + (sub * 32 + qr) * 64 + 32 + lr];
        float* orow =
            out + (uint64_t)(b * 2048 + qrow0 + sub * 32 + qr) * 1024 + h * 64 + lr;
        orow[0] = o0 * iv;
        orow[32] = o1 * iv;
      }
    }
  }
}

// ---------- launcher ----------
extern "C" void kernel_launch(void* const* d_in, const int* in_sizes, int n_in,
                              void* d_out, int out_size, void* d_ws, size_t ws_size,
                              hipStream_t stream) {
  const float* x = (const float*)d_in[0];
  const float* wq = (const float*)d_in[1];
  const float* wkv = (const float*)d_in[2];
  const float* kscale = (const float*)d_in[3];
  float* out = (float*)d_out;
  char* ws = (char*)d_ws;
  uint16_t* xb = (uint16_t*)(ws);                     // 8 MB  [4096][1024] bf16
  uint16_t* wt = (uint16_t*)(ws + (8ull << 20));      // 3 MB  [1536][1024] bf16
  uint16_t* q_ws = (uint16_t*)(ws + (11ull << 20));   // 8 MB  [2][16][2048][64]
  uint16_t* kf_ws = (uint16_t*)(ws + (19ull << 20));  // 2 MB  K fragments
  uint16_t* vf_ws = (uint16_t*)(ws + (21ull << 20));  // 2 MB  V fragments

  // allow 128 KB dynamic LDS for the attention kernel
  static bool attr_set = false;
  if (!attr_set) {
    (void)hipFuncSetAttribute((const void*)k_attn,
                              hipFuncAttributeMaxDynamicSharedMemorySize, 131072);
    attr_set = true;
  }

  k_convert<<<2432, 256, 0, stream>>>(x, wq, wkv, xb, wt);
  k_proj_gemm<<<768, 256, 0, stream>>>(xb, wt, kscale, q_ws, kf_ws, vf_ws);
  k_attn<<<256, 512, 131072, stream>>>(q_ws, kf_ws, vf_ws, out);
}